// Round 6
// baseline (99.080 us; speedup 1.0000x reference)
//
#include <hip/hip_runtime.h>
#include <stdio.h>

// Sizes fixed by the reference
#define H 4
#define B 8192
#define F 64
#define ALPHA 0.2f
#define NB 4096
#define DMIN (-8.0f)
#define DSCALE 256.0f    // NB / 16 over [-8, 8); clamp keeps monotonicity -> exact
#define TSZ 32
#define NTL (B / TSZ)    // 256 tiles per head
#define PELD 132         // PE row: 64 (e^d*hp) + 64 (e^.2d*hp) + 2 scalar prefixes

__device__ __forceinline__ int bucket_of(float x)
{
  int b = (int)((x - DMIN) * DSCALE);   // monotone non-decreasing in x
  return min(max(b, 0), NB - 1);
}

// -------------------------------------------------------------------------
// K1: h_prime = h @ w per head; s = hp.a_src, d = hp.a_dst.
__global__ __launch_bounds__(256) void k_hprime(
    const float* __restrict__ h, const float* __restrict__ w,
    const float* __restrict__ a_src, const float* __restrict__ a_dst,
    float* __restrict__ hp, float* __restrict__ s, float* __restrict__ d)
{
  int head = blockIdx.y;
  int row0 = blockIdx.x * 64;
  __shared__ float wl[F * F];   // 16 KB
  __shared__ float hl[64 * F];  // 16 KB
  const float4* wsrc = (const float4*)(w + (size_t)head * F * F);
  const float4* hsrc = (const float4*)(h + (size_t)row0 * F);
  float4* wl4 = (float4*)wl;
  float4* hl4 = (float4*)hl;
  for (int t = threadIdx.x; t < F * F / 4; t += 256) { wl4[t] = wsrc[t]; hl4[t] = hsrc[t]; }
  __syncthreads();
  int o  = threadIdx.x & 63;
  int rb = threadIdx.x >> 6;  // wave id: owns rows {rb, 4+rb, ..., 60+rb}
  float as = a_src[head * F + o];
  float ad = a_dst[head * F + o];
  float acc[16];
#pragma unroll
  for (int rg = 0; rg < 16; ++rg) acc[rg] = 0.f;
#pragma unroll 16
  for (int i = 0; i < F; ++i) {
    float wv = wl[i * F + o];              // stride-1 across lanes: conflict-free
#pragma unroll
    for (int rg = 0; rg < 16; ++rg)        // broadcast reads: conflict-free
      acc[rg] = fmaf(hl[(rg * 4 + rb) * F + i], wv, acc[rg]);
  }
#pragma unroll
  for (int rg = 0; rg < 16; ++rg) {
    int r = row0 + rg * 4 + rb;
    hp[((size_t)head * B + r) * F + o] = acc[rg];
    float vs = acc[rg] * as, vd = acc[rg] * ad;
#pragma unroll
    for (int off = 32; off; off >>= 1) { vs += __shfl_down(vs, off); vd += __shfl_down(vd, off); }
    if (o == 0) {
      s[(size_t)head * B + r] = vs;
      d[(size_t)head * B + r] = vd;
    }
  }
}

// -------------------------------------------------------------------------
// K2: fused per-head prep, all in LDS (96 KB): histogram -> exclusive scan ->
// counting-sort scatter -> exact in-bucket rank sort -> ds2/js2/bstart.
// Strict total order via (d, idx) lexicographic => valid permutation incl. ties.
__global__ __launch_bounds__(1024) void k_prep(
    const float* __restrict__ d, int* __restrict__ bstart,
    float* __restrict__ ds2, int* __restrict__ js2)
{
  int head = blockIdx.x;
  int tid = threadIdx.x;
  __shared__ int   hist[NB];    // 16 KB
  __shared__ int   cur[NB];     // 16 KB
  __shared__ float dls[B];      // 32 KB
  __shared__ int   ils[B];      // 32 KB
  __shared__ int wtot[16], woff[16];
  const float* dh = d + (size_t)head * B;
  float v[8];
#pragma unroll
  for (int t = 0; t < 8; ++t) v[t] = dh[tid + t * 1024];
#pragma unroll
  for (int t = 0; t < NB / 1024; ++t) hist[tid + t * 1024] = 0;
  __syncthreads();
#pragma unroll
  for (int t = 0; t < 8; ++t) atomicAdd(&hist[bucket_of(v[t])], 1);
  __syncthreads();
  // exclusive scan of 4096 counts: 4 per thread + wave shuffle scan + LDS combine
  int h0 = hist[4 * tid], h1 = hist[4 * tid + 1], h2 = hist[4 * tid + 2], h3 = hist[4 * tid + 3];
  int sum = h0 + h1 + h2 + h3;
  int lane = tid & 63, wid = tid >> 6;
  int run = sum;
#pragma unroll
  for (int off = 1; off < 64; off <<= 1) {
    int u = __shfl_up(run, off);
    if (lane >= off) run += u;
  }
  if (lane == 63) wtot[wid] = run;
  __syncthreads();
  if (tid < 16) {
    int off = 0;
    for (int j = 0; j < tid; ++j) off += wtot[j];
    woff[tid] = off;
  }
  __syncthreads();
  int excl = woff[wid] + run - sum;
  int e0 = excl, e1 = e0 + h0, e2 = e1 + h1, e3 = e2 + h2;
  cur[4 * tid] = e0; cur[4 * tid + 1] = e1; cur[4 * tid + 2] = e2; cur[4 * tid + 3] = e3;
  int bb = head * (NB + 1);
  bstart[bb + 4 * tid] = e0; bstart[bb + 4 * tid + 1] = e1;
  bstart[bb + 4 * tid + 2] = e2; bstart[bb + 4 * tid + 3] = e3;
  if (tid == 1023) bstart[bb + NB] = e3 + h3;   // == B
  __syncthreads();
  // scatter into LDS by bucket
#pragma unroll
  for (int t = 0; t < 8; ++t) {
    int b = bucket_of(v[t]);
    int pos = atomicAdd(&cur[b], 1);
    dls[pos] = v[t];
    ils[pos] = tid + t * 1024;
  }
  __syncthreads();
  // rank sort within bucket (post-scatter: cur[b] == end(b)); write global sorted
  size_t gb = (size_t)head * B;
#pragma unroll
  for (int t = 0; t < 8; ++t) {
    int e = tid + t * 1024;
    float dv = dls[e]; int iv = ils[e];
    int b = bucket_of(dv);
    int k0 = b ? cur[b - 1] : 0;
    int k1 = cur[b];
    int rank = 0;
    for (int k = k0; k < k1; ++k) {
      float d2 = dls[k]; int i2 = ils[k];
      rank += (d2 < dv) || (d2 == dv && i2 < iv);
    }
    ds2[gb + k0 + rank] = dv;
    js2[gb + k0 + rank] = iv;
  }
}

// -------------------------------------------------------------------------
// K3: per-tile sums of {e^d*hp, e^.2d*hp, e^d, e^.2d} over sorted order.
__global__ __launch_bounds__(256) void k_peA(
    const float* __restrict__ ds2, const int* __restrict__ js2,
    const float* __restrict__ hp, float* __restrict__ TS)
{
  int head = blockIdx.y;
  int tile = blockIdx.x * 4 + (threadIdx.x >> 6);
  int o = threadIdx.x & 63;
  const float* dsh = ds2 + (size_t)head * B;
  const int*   jsh = js2 + (size_t)head * B;
  const float* hph = hp + (size_t)head * B * F;
  float a1 = 0.f, a2 = 0.f, s1 = 0.f, s2 = 0.f;
#pragma unroll 8
  for (int j = 0; j < TSZ; ++j) {
    int k = tile * TSZ + j;
    float dv = dsh[k];                     // uniform
    float e1 = expf(dv), e2 = expf(ALPHA * dv);
    float hv = hph[(size_t)jsh[k] * F + o];
    a1 = fmaf(e1, hv, a1); a2 = fmaf(e2, hv, a2);
    s1 += e1; s2 += e2;
  }
  float* row = TS + ((size_t)head * NTL + tile) * PELD;
  row[o] = a1; row[64 + o] = a2;
  if (o == 0) { row[128] = s1; row[129] = s2; }
}

// -------------------------------------------------------------------------
// K4: write per-element exclusive prefix rows PE[k][132]; tile-prefix computed
// in-block (4 waves split the preceding TS rows; LDS combine; wave w adds
// rows [t0, t0+w)). The wave owning tile NTL-1 also writes per-head totals.
__global__ __launch_bounds__(256) void k_peC(
    const float* __restrict__ ds2, const int* __restrict__ js2,
    const float* __restrict__ hp, const float* __restrict__ TS,
    float* __restrict__ PE, float* __restrict__ totals)
{
  int head = blockIdx.y;
  int t0 = blockIdx.x * 4;
  int o = threadIdx.x & 63, wv = threadIdx.x >> 6;
  __shared__ float chA[4][64], chB[4][64], chS[4][2];
  const float* tsh = TS + (size_t)head * NTL * PELD;
  // phase 1: wave wv sums its quarter of tiles [0, t0)
  int len = t0 / 4;
  float a1 = 0.f, a2 = 0.f, s1 = 0.f, s2 = 0.f;
  for (int t = wv * len; t < (wv + 1) * len; ++t) {
    const float* r = tsh + (size_t)t * PELD;
    a1 += r[o]; a2 += r[64 + o]; s1 += r[128]; s2 += r[129];
  }
  chA[wv][o] = a1; chB[wv][o] = a2;
  if (o == 0) { chS[wv][0] = s1; chS[wv][1] = s2; }
  __syncthreads();
  // phase 2: full prefix for my tile = all chunks + rows [t0, t0+wv)
  a1 = 0.f; a2 = 0.f; s1 = 0.f; s2 = 0.f;
#pragma unroll
  for (int c = 0; c < 4; ++c) {
    a1 += chA[c][o]; a2 += chB[c][o]; s1 += chS[c][0]; s2 += chS[c][1];
  }
  for (int t = t0; t < t0 + wv; ++t) {
    const float* r = tsh + (size_t)t * PELD;
    a1 += r[o]; a2 += r[64 + o]; s1 += r[128]; s2 += r[129];
  }
  // per-element exclusive prefix over my tile
  int tile = t0 + wv;
  const float* dsh = ds2 + (size_t)head * B;
  const int*   jsh = js2 + (size_t)head * B;
  const float* hph = hp + (size_t)head * B * F;
  for (int j = 0; j < TSZ; ++j) {
    int k = tile * TSZ + j;
    float* row = PE + ((size_t)head * B + k) * PELD;
    row[o] = a1; row[64 + o] = a2;
    if (o == 0) { row[128] = s1; row[129] = s2; }
    float dv = dsh[k];
    float e1 = expf(dv), e2 = expf(ALPHA * dv);
    float hv = hph[(size_t)jsh[k] * F + o];
    a1 = fmaf(e1, hv, a1); a2 = fmaf(e2, hv, a2);
    s1 += e1; s2 += e2;
  }
  if (tile == NTL - 1) {
    totals[head * PELD + o] = a1;
    totals[head * PELD + 64 + o] = a2;
    if (o == 0) { totals[head * PELD + 128] = s1; totals[head * PELD + 129] = s2; }
  }
}

// -------------------------------------------------------------------------
// K5: per row i: pos = #{d < -s_i} via bucket start + short sorted walk,
// one PE row read, combine. Element-exact, no boundary arithmetic.
__global__ __launch_bounds__(256) void k_out(
    const float* __restrict__ s, const float* __restrict__ ds2,
    const float* __restrict__ PE, const float* __restrict__ totals,
    const int* __restrict__ bstart, const float* __restrict__ bias,
    float* __restrict__ out)
{
  int head = blockIdx.y;
  int i = blockIdx.x * 4 + (threadIdx.x >> 6);
  int o = threadIdx.x & 63;
  float si = s[(size_t)head * B + i];
  float t = -si;
  int q = bucket_of(t);
  int k  = bstart[head * (NB + 1) + q];
  int Eq = bstart[head * (NB + 1) + q + 1];
  const float* dsh = ds2 + (size_t)head * B;
  while (k < Eq && dsh[k] < t) ++k;        // wave-uniform short walk
  const float* row = (k < B) ? (PE + ((size_t)head * B + k) * PELD)
                             : (totals + head * PELD);
  float pe1 = row[o], pe2 = row[64 + o], p1 = row[128], p2 = row[129];
  float TE1 = totals[head * PELD + o];
  float T1  = totals[head * PELD + 128];
  float e1f = expf(si), e2f = expf(ALPHA * si);
  float denom = e2f * p2 + e1f * (T1 - p1);
  float num   = e2f * pe2 + e1f * (TE1 - pe1);
  out[(size_t)i * (H * F) + head * F + o] = num / denom + bias[o];
}

// -------------------------------------------------------------------------
extern "C" void kernel_launch(void* const* d_in, const int* in_sizes, int n_in,
                              void* d_out, int out_size, void* d_ws, size_t ws_size,
                              hipStream_t stream)
{
  const float* h     = (const float*)d_in[0];
  const float* w     = (const float*)d_in[1];
  const float* a_src = (const float*)d_in[2];
  const float* a_dst = (const float*)d_in[3];
  const float* bias  = (const float*)d_in[4];
  float* out = (float*)d_out;

  float* p = (float*)d_ws;
  float* hp     = p; p += (size_t)H * B * F;        // 8.4 MB
  float* s      = p; p += H * B;
  float* dd     = p; p += H * B;
  float* ds2    = p; p += H * B;
  int*   js2    = (int*)p; p += H * B;
  float* PE     = p; p += (size_t)H * B * PELD;     // 17.3 MB
  float* TS     = p; p += (size_t)H * NTL * PELD;
  float* totals = p; p += H * PELD;
  int* bstart   = (int*)p; p += H * (NB + 1);

  size_t need = (size_t)((char*)p - (char*)d_ws);
  if (ws_size < need) {
    fprintf(stderr, "kernel_launch: ws_size %zu < needed %zu\n", ws_size, need);
    return;
  }

  k_hprime<<<dim3(B / 64, H), 256, 0, stream>>>(h, w, a_src, a_dst, hp, s, dd);
  k_prep<<<H, 1024, 0, stream>>>(dd, bstart, ds2, js2);
  k_peA<<<dim3(NTL / 4, H), 256, 0, stream>>>(ds2, js2, hp, TS);
  k_peC<<<dim3(NTL / 4, H), 256, 0, stream>>>(ds2, js2, hp, TS, PE, totals);
  k_out<<<dim3(B / 4, H), 256, 0, stream>>>(s, ds2, PE, totals, bstart, bias, out);
}

// Round 7
// 84.142 us; speedup vs baseline: 1.1775x; 1.1775x over previous
//
#include <hip/hip_runtime.h>
#include <stdio.h>

// Sizes fixed by the reference
#define H 4
#define B 8192
#define F 64
#define ALPHA 0.2f
#define NB 4096
#define DMIN (-8.0f)
#define DSCALE 256.0f    // NB / 16 over [-8, 8); clamp keeps monotonicity -> exact
#define TSZ 32
#define NTL (B / TSZ)    // 256 tiles per head
#define PELD 132         // PE row: 64 (e^d*hp) + 64 (e^.2d*hp) + 2 scalar prefixes

__device__ __forceinline__ int bucket_of(float x)
{
  int b = (int)((x - DMIN) * DSCALE);   // monotone non-decreasing in x
  return min(max(b, 0), NB - 1);
}

// -------------------------------------------------------------------------
// K1: h_prime = h @ w per head; s = hp.a_src, d = hp.a_dst.
__global__ __launch_bounds__(256) void k_hprime(
    const float* __restrict__ h, const float* __restrict__ w,
    const float* __restrict__ a_src, const float* __restrict__ a_dst,
    float* __restrict__ hp, float* __restrict__ s, float* __restrict__ d)
{
  int head = blockIdx.y;
  int row0 = blockIdx.x * 64;
  __shared__ float wl[F * F];   // 16 KB
  __shared__ float hl[64 * F];  // 16 KB
  const float4* wsrc = (const float4*)(w + (size_t)head * F * F);
  const float4* hsrc = (const float4*)(h + (size_t)row0 * F);
  float4* wl4 = (float4*)wl;
  float4* hl4 = (float4*)hl;
  for (int t = threadIdx.x; t < F * F / 4; t += 256) { wl4[t] = wsrc[t]; hl4[t] = hsrc[t]; }
  __syncthreads();
  int o  = threadIdx.x & 63;
  int rb = threadIdx.x >> 6;  // wave id: owns rows {rb, 4+rb, ..., 60+rb}
  float as = a_src[head * F + o];
  float ad = a_dst[head * F + o];
  float acc[16];
#pragma unroll
  for (int rg = 0; rg < 16; ++rg) acc[rg] = 0.f;
#pragma unroll 16
  for (int i = 0; i < F; ++i) {
    float wv = wl[i * F + o];              // stride-1 across lanes: conflict-free
#pragma unroll
    for (int rg = 0; rg < 16; ++rg)        // broadcast reads: conflict-free
      acc[rg] = fmaf(hl[(rg * 4 + rb) * F + i], wv, acc[rg]);
  }
#pragma unroll
  for (int rg = 0; rg < 16; ++rg) {
    int r = row0 + rg * 4 + rb;
    hp[((size_t)head * B + r) * F + o] = acc[rg];
    float vs = acc[rg] * as, vd = acc[rg] * ad;
#pragma unroll
    for (int off = 32; off; off >>= 1) { vs += __shfl_down(vs, off); vd += __shfl_down(vd, off); }
    if (o == 0) {
      s[(size_t)head * B + r] = vs;
      d[(size_t)head * B + r] = vd;
    }
  }
}

// -------------------------------------------------------------------------
// K2: fused per-head prep, all in LDS (96 KB): histogram -> exclusive scan ->
// counting-sort scatter -> exact in-bucket rank sort -> ds2/js2/bstart.
// Strict total order via (d, idx) lexicographic => valid permutation incl. ties.
__global__ __launch_bounds__(1024) void k_prep(
    const float* __restrict__ d, int* __restrict__ bstart,
    float* __restrict__ ds2, int* __restrict__ js2)
{
  int head = blockIdx.x;
  int tid = threadIdx.x;
  __shared__ int   hist[NB];    // 16 KB
  __shared__ int   cur[NB];     // 16 KB
  __shared__ float dls[B];      // 32 KB
  __shared__ int   ils[B];      // 32 KB
  __shared__ int wtot[16], woff[16];
  const float* dh = d + (size_t)head * B;
  float v[8];
#pragma unroll
  for (int t = 0; t < 8; ++t) v[t] = dh[tid + t * 1024];
#pragma unroll
  for (int t = 0; t < NB / 1024; ++t) hist[tid + t * 1024] = 0;
  __syncthreads();
#pragma unroll
  for (int t = 0; t < 8; ++t) atomicAdd(&hist[bucket_of(v[t])], 1);
  __syncthreads();
  // exclusive scan of 4096 counts: 4 per thread + wave shuffle scan + LDS combine
  int h0 = hist[4 * tid], h1 = hist[4 * tid + 1], h2 = hist[4 * tid + 2], h3 = hist[4 * tid + 3];
  int sum = h0 + h1 + h2 + h3;
  int lane = tid & 63, wid = tid >> 6;
  int run = sum;
#pragma unroll
  for (int off = 1; off < 64; off <<= 1) {
    int u = __shfl_up(run, off);
    if (lane >= off) run += u;
  }
  if (lane == 63) wtot[wid] = run;
  __syncthreads();
  if (tid < 16) {
    int off = 0;
    for (int j = 0; j < tid; ++j) off += wtot[j];
    woff[tid] = off;
  }
  __syncthreads();
  int excl = woff[wid] + run - sum;
  int e0 = excl, e1 = e0 + h0, e2 = e1 + h1, e3 = e2 + h2;
  cur[4 * tid] = e0; cur[4 * tid + 1] = e1; cur[4 * tid + 2] = e2; cur[4 * tid + 3] = e3;
  int bb = head * (NB + 1);
  bstart[bb + 4 * tid] = e0; bstart[bb + 4 * tid + 1] = e1;
  bstart[bb + 4 * tid + 2] = e2; bstart[bb + 4 * tid + 3] = e3;
  if (tid == 1023) bstart[bb + NB] = e3 + h3;   // == B
  __syncthreads();
  // scatter into LDS by bucket
#pragma unroll
  for (int t = 0; t < 8; ++t) {
    int b = bucket_of(v[t]);
    int pos = atomicAdd(&cur[b], 1);
    dls[pos] = v[t];
    ils[pos] = tid + t * 1024;
  }
  __syncthreads();
  // rank sort within bucket (post-scatter: cur[b] == end(b)); write global sorted
  size_t gb = (size_t)head * B;
#pragma unroll
  for (int t = 0; t < 8; ++t) {
    int e = tid + t * 1024;
    float dv = dls[e]; int iv = ils[e];
    int b = bucket_of(dv);
    int k0 = b ? cur[b - 1] : 0;
    int k1 = cur[b];
    int rank = 0;
    for (int k = k0; k < k1; ++k) {
      float d2 = dls[k]; int i2 = ils[k];
      rank += (d2 < dv) || (d2 == dv && i2 < iv);
    }
    ds2[gb + k0 + rank] = dv;
    js2[gb + k0 + rank] = iv;
  }
}

// -------------------------------------------------------------------------
// K3: per-tile sums of {e^d*hp, e^.2d*hp, e^d, e^.2d} over sorted order.
__global__ __launch_bounds__(256) void k_peA(
    const float* __restrict__ ds2, const int* __restrict__ js2,
    const float* __restrict__ hp, float* __restrict__ TS)
{
  int head = blockIdx.y;
  int tile = blockIdx.x * 4 + (threadIdx.x >> 6);
  int o = threadIdx.x & 63;
  const float* dsh = ds2 + (size_t)head * B;
  const int*   jsh = js2 + (size_t)head * B;
  const float* hph = hp + (size_t)head * B * F;
  float a1 = 0.f, a2 = 0.f, s1 = 0.f, s2 = 0.f;
#pragma unroll 8
  for (int j = 0; j < TSZ; ++j) {
    int k = tile * TSZ + j;
    float dv = dsh[k];                     // uniform
    float e1 = expf(dv), e2 = expf(ALPHA * dv);
    float hv = hph[(size_t)jsh[k] * F + o];
    a1 = fmaf(e1, hv, a1); a2 = fmaf(e2, hv, a2);
    s1 += e1; s2 += e2;
  }
  float* row = TS + ((size_t)head * NTL + tile) * PELD;
  row[o] = a1; row[64 + o] = a2;
  if (o == 0) { row[128] = s1; row[129] = s2; }
}

// K4: exclusive scan of tile sums, one wave per (head, channel).
// Lane owns 4 consecutive tiles in registers -> no dependent-L2-RMW chain.
__global__ __launch_bounds__(64) void k_peB(
    float* __restrict__ TS, float* __restrict__ totals)
{
  int head = blockIdx.y;
  int c = blockIdx.x;       // 0..129
  int lane = threadIdx.x;
  float* base = TS + (size_t)head * NTL * PELD + c;
  int t0 = lane * 4;
  float v[4];
#pragma unroll
  for (int t = 0; t < 4; ++t) v[t] = base[(size_t)(t0 + t) * PELD];
  float sum = 0.f;
#pragma unroll
  for (int t = 0; t < 4; ++t) { sum += v[t]; v[t] = sum; }  // inclusive chunk prefix
  float run = sum;
#pragma unroll
  for (int off = 1; off < 64; off <<= 1) {
    float u = __shfl_up(run, off);
    if (lane >= off) run += u;
  }
  float excl = run - sum;
  if (lane == 63) totals[head * PELD + c] = run;
#pragma unroll
  for (int t = 0; t < 4; ++t)
    base[(size_t)(t0 + t) * PELD] = excl + (t == 0 ? 0.f : v[t - 1]);
}

// K5: write full per-element exclusive prefix rows PE[k][132].
__global__ __launch_bounds__(256) void k_peC(
    const float* __restrict__ ds2, const int* __restrict__ js2,
    const float* __restrict__ hp, const float* __restrict__ TS,
    float* __restrict__ PE)
{
  int head = blockIdx.y;
  int tile = blockIdx.x * 4 + (threadIdx.x >> 6);
  int o = threadIdx.x & 63;
  const float* dsh = ds2 + (size_t)head * B;
  const int*   jsh = js2 + (size_t)head * B;
  const float* hph = hp + (size_t)head * B * F;
  const float* trow = TS + ((size_t)head * NTL + tile) * PELD;
  float a1 = trow[o], a2 = trow[64 + o], s1 = trow[128], s2 = trow[129];
  for (int j = 0; j < TSZ; ++j) {
    int k = tile * TSZ + j;
    float* row = PE + ((size_t)head * B + k) * PELD;
    row[o] = a1; row[64 + o] = a2;
    if (o == 0) { row[128] = s1; row[129] = s2; }
    float dv = dsh[k];
    float e1 = expf(dv), e2 = expf(ALPHA * dv);
    float hv = hph[(size_t)jsh[k] * F + o];
    a1 = fmaf(e1, hv, a1); a2 = fmaf(e2, hv, a2);
    s1 += e1; s2 += e2;
  }
}

// -------------------------------------------------------------------------
// K6: per row i: pos = #{d < -s_i} via bucket start + short sorted walk,
// one PE row read, combine. Element-exact, no boundary arithmetic.
__global__ __launch_bounds__(256) void k_out(
    const float* __restrict__ s, const float* __restrict__ ds2,
    const float* __restrict__ PE, const float* __restrict__ totals,
    const int* __restrict__ bstart, const float* __restrict__ bias,
    float* __restrict__ out)
{
  int head = blockIdx.y;
  int i = blockIdx.x * 4 + (threadIdx.x >> 6);
  int o = threadIdx.x & 63;
  float si = s[(size_t)head * B + i];
  float t = -si;
  int q = bucket_of(t);
  int k  = bstart[head * (NB + 1) + q];
  int Eq = bstart[head * (NB + 1) + q + 1];
  const float* dsh = ds2 + (size_t)head * B;
  while (k < Eq && dsh[k] < t) ++k;        // wave-uniform short walk
  const float* row = (k < B) ? (PE + ((size_t)head * B + k) * PELD)
                             : (totals + head * PELD);
  float pe1 = row[o], pe2 = row[64 + o], p1 = row[128], p2 = row[129];
  float TE1 = totals[head * PELD + o];
  float T1  = totals[head * PELD + 128];
  float e1f = expf(si), e2f = expf(ALPHA * si);
  float denom = e2f * p2 + e1f * (T1 - p1);
  float num   = e2f * pe2 + e1f * (TE1 - pe1);
  out[(size_t)i * (H * F) + head * F + o] = num / denom + bias[o];
}

// -------------------------------------------------------------------------
extern "C" void kernel_launch(void* const* d_in, const int* in_sizes, int n_in,
                              void* d_out, int out_size, void* d_ws, size_t ws_size,
                              hipStream_t stream)
{
  const float* h     = (const float*)d_in[0];
  const float* w     = (const float*)d_in[1];
  const float* a_src = (const float*)d_in[2];
  const float* a_dst = (const float*)d_in[3];
  const float* bias  = (const float*)d_in[4];
  float* out = (float*)d_out;

  float* p = (float*)d_ws;
  float* hp     = p; p += (size_t)H * B * F;        // 8.4 MB
  float* s      = p; p += H * B;
  float* dd     = p; p += H * B;
  float* ds2    = p; p += H * B;
  int*   js2    = (int*)p; p += H * B;
  float* PE     = p; p += (size_t)H * B * PELD;     // 17.3 MB
  float* TS     = p; p += (size_t)H * NTL * PELD;
  float* totals = p; p += H * PELD;
  int* bstart   = (int*)p; p += H * (NB + 1);

  size_t need = (size_t)((char*)p - (char*)d_ws);
  if (ws_size < need) {
    fprintf(stderr, "kernel_launch: ws_size %zu < needed %zu\n", ws_size, need);
    return;
  }

  k_hprime<<<dim3(B / 64, H), 256, 0, stream>>>(h, w, a_src, a_dst, hp, s, dd);
  k_prep<<<H, 1024, 0, stream>>>(dd, bstart, ds2, js2);
  k_peA<<<dim3(NTL / 4, H), 256, 0, stream>>>(ds2, js2, hp, TS);
  k_peB<<<dim3(130, H), 64, 0, stream>>>(TS, totals);
  k_peC<<<dim3(NTL / 4, H), 256, 0, stream>>>(ds2, js2, hp, TS, PE);
  k_out<<<dim3(B / 4, H), 256, 0, stream>>>(s, ds2, PE, totals, bstart, bias, out);
}

// Round 8
// 74.814 us; speedup vs baseline: 1.3243x; 1.1247x over previous
//
#include <hip/hip_runtime.h>
#include <stdio.h>

// Sizes fixed by the reference
#define H 4
#define B 8192
#define F 64
#define ALPHA 0.2f
#define NB 4096
#define DMIN (-8.0f)
#define DSCALE 256.0f    // NB / 16 over [-8, 8); clamp keeps monotonicity -> exact
#define TSZ 16
#define NTL (B / TSZ)    // 512 tiles per head
#define PELD 132         // PE row: 64 (e^d*hp) + 64 (e^.2d*hp) + 2 scalar prefixes

__device__ __forceinline__ int bucket_of(float x)
{
  int b = (int)((x - DMIN) * DSCALE);   // monotone non-decreasing in x
  return min(max(b, 0), NB - 1);
}

// -------------------------------------------------------------------------
// K1: h_prime = h @ w per head; s = hp.a_src, d = hp.a_dst.
// Inner loop: float4 broadcast h-reads -> 20 LDS ops per 64 FMA (was 68).
__global__ __launch_bounds__(256) void k_hprime(
    const float* __restrict__ h, const float* __restrict__ w,
    const float* __restrict__ a_src, const float* __restrict__ a_dst,
    float* __restrict__ hp, float* __restrict__ s, float* __restrict__ d)
{
  int head = blockIdx.y;
  int row0 = blockIdx.x * 64;
  __shared__ float wl[F * F];   // 16 KB
  __shared__ float hl[64 * F];  // 16 KB
  const float4* wsrc = (const float4*)(w + (size_t)head * F * F);
  const float4* hsrc = (const float4*)(h + (size_t)row0 * F);
  float4* wl4 = (float4*)wl;
  float4* hl4 = (float4*)hl;
  for (int t = threadIdx.x; t < F * F / 4; t += 256) { wl4[t] = wsrc[t]; hl4[t] = hsrc[t]; }
  __syncthreads();
  int o  = threadIdx.x & 63;
  int rb = threadIdx.x >> 6;  // wave id: owns rows {rb, 4+rb, ..., 60+rb}
  float as = a_src[head * F + o];
  float ad = a_dst[head * F + o];
  float acc[16];
#pragma unroll
  for (int rg = 0; rg < 16; ++rg) acc[rg] = 0.f;
#pragma unroll 4
  for (int i4 = 0; i4 < F / 4; ++i4) {
    float w0 = wl[(4 * i4 + 0) * F + o];   // stride-1 across lanes: conflict-free
    float w1 = wl[(4 * i4 + 1) * F + o];
    float w2 = wl[(4 * i4 + 2) * F + o];
    float w3 = wl[(4 * i4 + 3) * F + o];
#pragma unroll
    for (int rg = 0; rg < 16; ++rg) {      // broadcast b128 reads: conflict-free
      float4 h4 = *((const float4*)(hl + (rg * 4 + rb) * F) + i4);
      acc[rg] = fmaf(h4.x, w0, fmaf(h4.y, w1, fmaf(h4.z, w2, fmaf(h4.w, w3, acc[rg]))));
    }
  }
#pragma unroll
  for (int rg = 0; rg < 16; ++rg) {
    int r = row0 + rg * 4 + rb;
    hp[((size_t)head * B + r) * F + o] = acc[rg];
    float vs = acc[rg] * as, vd = acc[rg] * ad;
#pragma unroll
    for (int off = 32; off; off >>= 1) { vs += __shfl_down(vs, off); vd += __shfl_down(vd, off); }
    if (o == 0) {
      s[(size_t)head * B + r] = vs;
      d[(size_t)head * B + r] = vd;
    }
  }
}

// -------------------------------------------------------------------------
// K2: per head (1 block of 1024): LDS histogram of d -> exclusive scan ->
// bstart + scatter cursors.
__global__ __launch_bounds__(1024) void k_hist_scan(
    const float* __restrict__ d, int* __restrict__ bstart, int* __restrict__ gcur)
{
  int head = blockIdx.x;
  int tid = threadIdx.x;
  __shared__ int hist[NB];     // 16 KB
  __shared__ int wtot[16], woff[16];
#pragma unroll
  for (int t = 0; t < NB / 1024; ++t) hist[tid + t * 1024] = 0;
  __syncthreads();
  const float* dh = d + (size_t)head * B;
#pragma unroll
  for (int t = 0; t < B / 1024; ++t)
    atomicAdd(&hist[bucket_of(dh[tid + t * 1024])], 1);
  __syncthreads();
  int h0 = hist[4 * tid], h1 = hist[4 * tid + 1], h2 = hist[4 * tid + 2], h3 = hist[4 * tid + 3];
  int sum = h0 + h1 + h2 + h3;
  int lane = tid & 63, wid = tid >> 6;
  int run = sum;
#pragma unroll
  for (int off = 1; off < 64; off <<= 1) {
    int v = __shfl_up(run, off);
    if (lane >= off) run += v;
  }
  if (lane == 63) wtot[wid] = run;
  __syncthreads();
  if (tid < 16) {
    int off = 0;
    for (int j = 0; j < tid; ++j) off += wtot[j];
    woff[tid] = off;
  }
  __syncthreads();
  int excl = woff[wid] + run - sum;
  int base = head * (NB + 1) + 4 * tid;
  int gbase = head * NB + 4 * tid;
  int e0 = excl, e1 = e0 + h0, e2 = e1 + h1, e3 = e2 + h2;
  bstart[base] = e0; bstart[base + 1] = e1; bstart[base + 2] = e2; bstart[base + 3] = e3;
  gcur[gbase] = e0; gcur[gbase + 1] = e1; gcur[gbase + 2] = e2; gcur[gbase + 3] = e3;
  if (tid == 1023) bstart[head * (NB + 1) + NB] = e3 + h3;   // == B
}

// -------------------------------------------------------------------------
// K3: bucket scatter (order within bucket arbitrary; k_sort fixes it).
__global__ __launch_bounds__(512) void k_scatter(
    const float* __restrict__ d, int* __restrict__ gcur,
    float* __restrict__ ds, int* __restrict__ is)
{
  int head = blockIdx.y;
  int i = blockIdx.x * 512 + threadIdx.x;
  float v = d[(size_t)head * B + i];
  int b = bucket_of(v);
  int pos = atomicAdd(&gcur[head * NB + b], 1);
  ds[(size_t)head * B + pos] = v;
  is[(size_t)head * B + pos] = i;
}

// -------------------------------------------------------------------------
// K4: exact rank sort within each bucket -> fully sorted (d, idx) per head.
// Strict total order via (d, idx) lexicographic => valid permutation incl. ties.
__global__ __launch_bounds__(256) void k_sort(
    const float* __restrict__ dsort, const int* __restrict__ isort,
    const int* __restrict__ bstart, float* __restrict__ ds2, int* __restrict__ js2)
{
  int head = blockIdx.y;
  int b = blockIdx.x * 4 + (threadIdx.x >> 6);
  int lane = threadIdx.x & 63;
  int k0 = bstart[head * (NB + 1) + b];
  int k1 = bstart[head * (NB + 1) + b + 1];
  const float* dh = dsort + (size_t)head * B;
  const int*   ih = isort + (size_t)head * B;
  for (int e = k0 + lane; e < k1; e += 64) {
    float dv = dh[e]; int iv = ih[e];
    int rank = 0;
    for (int k = k0; k < k1; ++k) {        // wave-uniform broadcast loads
      float d2 = dh[k]; int i2 = ih[k];
      rank += (d2 < dv) || (d2 == dv && i2 < iv);
    }
    ds2[(size_t)head * B + k0 + rank] = dv;
    js2[(size_t)head * B + k0 + rank] = iv;
  }
}

// -------------------------------------------------------------------------
// K5a: per-tile sums of {e^d*hp, e^.2d*hp, e^d, e^.2d} over sorted order.
// All 16 gathers issued before accumulation (static unroll, deep ILP).
__global__ __launch_bounds__(256) void k_peA(
    const float* __restrict__ ds2, const int* __restrict__ js2,
    const float* __restrict__ hp, float* __restrict__ TS)
{
  int head = blockIdx.y;
  int tile = blockIdx.x * 4 + (threadIdx.x >> 6);
  int o = threadIdx.x & 63;
  int k0 = tile * TSZ;
  const float* dsh = ds2 + (size_t)head * B;
  const int*   jsh = js2 + (size_t)head * B;
  const float* hph = hp + (size_t)head * B * F;
  float e1[TSZ], e2[TSZ], hv[TSZ];
  int jj[TSZ];
#pragma unroll
  for (int j = 0; j < TSZ; ++j) jj[j] = jsh[k0 + j];
#pragma unroll
  for (int j = 0; j < TSZ; ++j) hv[j] = hph[(size_t)jj[j] * F + o];
#pragma unroll
  for (int j = 0; j < TSZ; ++j) {
    float dv = dsh[k0 + j];
    e1[j] = expf(dv); e2[j] = expf(ALPHA * dv);
  }
  float a1 = 0.f, a2 = 0.f, s1 = 0.f, s2 = 0.f;
#pragma unroll
  for (int j = 0; j < TSZ; ++j) {
    a1 = fmaf(e1[j], hv[j], a1);
    a2 = fmaf(e2[j], hv[j], a2);
    s1 += e1[j]; s2 += e2[j];
  }
  float* row = TS + ((size_t)head * NTL + tile) * PELD;
  row[o] = a1; row[64 + o] = a2;
  if (o == 0) { row[128] = s1; row[129] = s2; }
}

// K5b: exclusive scan of tile sums, one wave per (head, channel).
// Lane owns 8 consecutive tiles in registers -> no dependent-L2-RMW chain.
__global__ __launch_bounds__(64) void k_peB(
    float* __restrict__ TS, float* __restrict__ totals)
{
  int head = blockIdx.y;
  int c = blockIdx.x;       // 0..129
  int lane = threadIdx.x;
  float* base = TS + (size_t)head * NTL * PELD + c;
  int t0 = lane * 8;
  float v[8];
#pragma unroll
  for (int t = 0; t < 8; ++t) v[t] = base[(size_t)(t0 + t) * PELD];
  float sum = 0.f;
#pragma unroll
  for (int t = 0; t < 8; ++t) { sum += v[t]; v[t] = sum; }  // inclusive chunk prefix
  float run = sum;
#pragma unroll
  for (int off = 1; off < 64; off <<= 1) {
    float u = __shfl_up(run, off);
    if (lane >= off) run += u;
  }
  float excl = run - sum;
  if (lane == 63) totals[head * PELD + c] = run;
#pragma unroll
  for (int t = 0; t < 8; ++t)
    base[(size_t)(t0 + t) * PELD] = excl + (t == 0 ? 0.f : v[t - 1]);
}

// K5c: write full per-element exclusive prefix rows PE[k][132].
__global__ __launch_bounds__(256) void k_peC(
    const float* __restrict__ ds2, const int* __restrict__ js2,
    const float* __restrict__ hp, const float* __restrict__ TS,
    float* __restrict__ PE)
{
  int head = blockIdx.y;
  int tile = blockIdx.x * 4 + (threadIdx.x >> 6);
  int o = threadIdx.x & 63;
  int k0 = tile * TSZ;
  const float* dsh = ds2 + (size_t)head * B;
  const int*   jsh = js2 + (size_t)head * B;
  const float* hph = hp + (size_t)head * B * F;
  float e1[TSZ], e2[TSZ], hv[TSZ];
  int jj[TSZ];
#pragma unroll
  for (int j = 0; j < TSZ; ++j) jj[j] = jsh[k0 + j];
#pragma unroll
  for (int j = 0; j < TSZ; ++j) hv[j] = hph[(size_t)jj[j] * F + o];
#pragma unroll
  for (int j = 0; j < TSZ; ++j) {
    float dv = dsh[k0 + j];
    e1[j] = expf(dv); e2[j] = expf(ALPHA * dv);
  }
  const float* trow = TS + ((size_t)head * NTL + tile) * PELD;
  float a1 = trow[o], a2 = trow[64 + o], s1 = trow[128], s2 = trow[129];
#pragma unroll
  for (int j = 0; j < TSZ; ++j) {
    float* row = PE + ((size_t)head * B + k0 + j) * PELD;
    row[o] = a1; row[64 + o] = a2;
    if (o == 0) { row[128] = s1; row[129] = s2; }
    a1 = fmaf(e1[j], hv[j], a1);
    a2 = fmaf(e2[j], hv[j], a2);
    s1 += e1[j]; s2 += e2[j];
  }
}

// -------------------------------------------------------------------------
// K6: per row i: pos = #{d < -s_i} via bucket start + short sorted walk,
// one PE row read, combine. Element-exact, no boundary arithmetic.
__global__ __launch_bounds__(256) void k_out(
    const float* __restrict__ s, const float* __restrict__ ds2,
    const float* __restrict__ PE, const float* __restrict__ totals,
    const int* __restrict__ bstart, const float* __restrict__ bias,
    float* __restrict__ out)
{
  int head = blockIdx.y;
  int i = blockIdx.x * 4 + (threadIdx.x >> 6);
  int o = threadIdx.x & 63;
  float si = s[(size_t)head * B + i];
  float t = -si;
  int q = bucket_of(t);
  int k  = bstart[head * (NB + 1) + q];
  int Eq = bstart[head * (NB + 1) + q + 1];
  const float* dsh = ds2 + (size_t)head * B;
  while (k < Eq && dsh[k] < t) ++k;        // wave-uniform short walk
  const float* row = (k < B) ? (PE + ((size_t)head * B + k) * PELD)
                             : (totals + head * PELD);
  float pe1 = row[o], pe2 = row[64 + o], p1 = row[128], p2 = row[129];
  float TE1 = totals[head * PELD + o];
  float T1  = totals[head * PELD + 128];
  float e1f = expf(si), e2f = expf(ALPHA * si);
  float denom = e2f * p2 + e1f * (T1 - p1);
  float num   = e2f * pe2 + e1f * (TE1 - pe1);
  out[(size_t)i * (H * F) + head * F + o] = num / denom + bias[o];
}

// -------------------------------------------------------------------------
extern "C" void kernel_launch(void* const* d_in, const int* in_sizes, int n_in,
                              void* d_out, int out_size, void* d_ws, size_t ws_size,
                              hipStream_t stream)
{
  const float* h     = (const float*)d_in[0];
  const float* w     = (const float*)d_in[1];
  const float* a_src = (const float*)d_in[2];
  const float* a_dst = (const float*)d_in[3];
  const float* bias  = (const float*)d_in[4];
  float* out = (float*)d_out;

  float* p = (float*)d_ws;
  float* hp     = p; p += (size_t)H * B * F;        // 8.4 MB
  float* s      = p; p += H * B;
  float* dd     = p; p += H * B;
  float* dsort  = p; p += H * B;
  int*   isort  = (int*)p; p += H * B;
  float* ds2    = p; p += H * B;
  int*   js2    = (int*)p; p += H * B;
  float* PE     = p; p += (size_t)H * B * PELD;     // 17.3 MB
  float* TS     = p; p += (size_t)H * NTL * PELD;   // 1.1 MB
  float* totals = p; p += H * PELD;
  int* bstart   = (int*)p; p += H * (NB + 1);
  int* gcur     = (int*)p; p += H * NB;

  size_t need = (size_t)((char*)p - (char*)d_ws);
  if (ws_size < need) {
    fprintf(stderr, "kernel_launch: ws_size %zu < needed %zu\n", ws_size, need);
    return;
  }

  k_hprime<<<dim3(B / 64, H), 256, 0, stream>>>(h, w, a_src, a_dst, hp, s, dd);
  k_hist_scan<<<H, 1024, 0, stream>>>(dd, bstart, gcur);
  k_scatter<<<dim3(B / 512, H), 512, 0, stream>>>(dd, gcur, dsort, isort);
  k_sort<<<dim3(NB / 4, H), 256, 0, stream>>>(dsort, isort, bstart, ds2, js2);
  k_peA<<<dim3(NTL / 4, H), 256, 0, stream>>>(ds2, js2, hp, TS);
  k_peB<<<dim3(130, H), 64, 0, stream>>>(TS, totals);
  k_peC<<<dim3(NTL / 4, H), 256, 0, stream>>>(ds2, js2, hp, TS, PE);
  k_out<<<dim3(B / 4, H), 256, 0, stream>>>(s, ds2, PE, totals, bstart, bias, out);
}